// Round 13
// baseline (765.896 us; speedup 1.0000x reference)
//
#include <hip/hip_runtime.h>

#define BATCH 8192
#define V 512
#define N1 513
#define NCH 32           // chunks of 16 variables
#define RB 32            // rows per block -> grid 256 (1 block/CU)
#define NT 1024          // 16 waves; wave w owns variable v0+w each chunk
#define PKS 520          // Phi row stride (bf16 elems)

typedef __bf16 bf16_t;
typedef bf16_t bf16x8 __attribute__((ext_vector_type(8)));
typedef float f32x4 __attribute__((ext_vector_type(4)));

// workspace (all mat=1 data PRE-NEGATED so every reduce is a max):
//  Mb : bf16, per-variable fragment pack. var v (cc=v>>4, nkb=(cc+1)>>1):
//       vbase = 16384*(cc*cc>>2) + (v&15)*1024*nkb
//       elem  = vbase + mat*512*nkb + kb*512 + lane*8 + jj
//             = +/- M[v][c=lane&15][k=kb*32+8*(lane>>4)+jj], 0 if k>=16*cc
//  DvT: f32 [vcol][w][c][mat]  (within-chunk coupling coefficients)
//  Bt : f32 [v][c][mat]        (bias column)
#define MB_ELEMS 4194304ull
#define DVT_OFF  (MB_ELEMS * 2ull)
#define BT_OFF   (DVT_OFF + 1048576ull)

__device__ __forceinline__ f32x4 mfma16(bf16x8 a, bf16x8 b, f32x4 c) {
    return __builtin_amdgcn_mfma_f32_16x16x32_bf16(a, b, c, 0, 0, 0);
}
__device__ __forceinline__ f32x4 shflx4(f32x4 x, int m) {
    f32x4 r;
    r[0] = __shfl_xor(x[0], m, 64);
    r[1] = __shfl_xor(x[1], m, 64);
    r[2] = __shfl_xor(x[2], m, 64);
    r[3] = __shfl_xor(x[3], m, 64);
    return r;
}
__device__ __forceinline__ f32x4 splat4(float s) { return f32x4{s, s, s, s}; }

// ---- repack: blocks 0..7935 Mb; 7936..8959 DvT; 8960..9023 Bt ------------------
__global__ __launch_bounds__(256)
void repack_all(const float* __restrict__ pos, const float* __restrict__ neg,
                bf16_t* __restrict__ Mb, float* __restrict__ DvT,
                float* __restrict__ Bt)
{
    const int bx = blockIdx.x;
    if (bx < 7936) {
        const int v   = 16 + (bx >> 4);
        const int kb  = bx & 15;
        const int cc  = v >> 4;
        const int nkb = (cc + 1) >> 1;
        if (kb >= nkb) return;
        const int klen = 16 * cc;
        const size_t vbase = 16384ull * (size_t)((cc * cc) >> 2)
                           + (size_t)(v & 15) * 1024ull * nkb
                           + (size_t)kb * 512ull;
        for (int e = threadIdx.x; e < 1024; e += 256) {
            const int mat = e >> 9, s = (e >> 3) & 63, jj = e & 7;
            const int c = s & 15, q = s >> 4;
            const int k = kb * 32 + 8 * q + jj;
            const float* src = mat ? neg : pos;
            float x = (k < klen) ? src[(size_t)(v * 16 + c) * N1 + k] : 0.0f;
            if (mat) x = -x;
            Mb[vbase + (size_t)mat * 512ull * nkb + (e & 511)] = (bf16_t)x;
        }
    } else if (bx < 8960) {
        const int e = (bx - 7936) * 256 + threadIdx.x;       // 262144
        const int mat = e & 1, c = (e >> 1) & 15, w = (e >> 5) & 15;
        const int vcol = e >> 9;
        const int v = (vcol & ~15) + w;
        const float* src = mat ? neg : pos;
        const float x = src[(size_t)(v * 16 + c) * N1 + vcol]; // 0 if vcol>=v (pre-masked)
        DvT[e] = mat ? -x : x;
    } else {
        const int e = (bx - 8960) * 256 + threadIdx.x;       // 16384
        const int mat = e & 1, c = (e >> 1) & 15, v = e >> 5;
        const float* src = mat ? neg : pos;
        const float x = src[(size_t)(v * 16 + c) * N1 + V];
        Bt[e] = mat ? -x : x;
    }
}

// ---- async main kernel: NO per-chunk barriers ----------------------------------
// Wave w owns variable v0+w of every chunk. Its MFMA C-fragment (acc[half][mat])
// already holds all 32 rows x 16 c for its variable -> no LDS transpose needed.
// Serial propagation via LDS: Pc[vl][32 rows] + monotonic epoch flags[16].
// Wave w per chunk cc: [wait flag15>=cc; final k-block] -> for vl<w {wait
// flag[vl]>cc; rank-1 from Pc[vl]} -> xor-reduce over c-lanes -> publish
// (Pc[w], Phi column, flag[w]=cc+1) -> bias+bulk GEMM of chunk cc+1 (cols<16cc,
// all ancient -> no wait). Deadlock-free: wave 0 never waits in-chain.
__global__ __launch_bounds__(NT)
void shield_async(const float* __restrict__ preds,
                  const bf16_t* __restrict__ Mb,
                  const float* __restrict__ DvT, const float* __restrict__ Bt,
                  float* __restrict__ out)
{
    __shared__ bf16_t Phi[RB * PKS];   // 33,280 B
    __shared__ float  Pc[16 * 32];     //  2,048 B
    __shared__ int    flags[16];

    const int tid  = threadIdx.x;
    const int b0   = blockIdx.x * RB;
    const int lane = tid & 63;
    const int w    = tid >> 6;          // 0..15: wave id = within-chunk variable
    const int cq   = lane & 15;
    const int q    = lane >> 4;

    if (tid < 16) flags[tid] = 0;

    // ---- load preds -> Phi ----
    {
        const int r = tid >> 5, seg = tid & 31;
        const float* prow = preds + (size_t)(b0 + r) * V + seg * 16;
        #pragma unroll
        for (int k = 0; k < 16; k += 4) {
            const float4 p4 = *(const float4*)(prow + k);
            const int n = seg * 16 + k;
            Phi[r * PKS + n + 0] = (bf16_t)p4.x;
            Phi[r * PKS + n + 1] = (bf16_t)p4.y;
            Phi[r * PKS + n + 2] = (bf16_t)p4.z;
            Phi[r * PKS + n + 3] = (bf16_t)p4.w;
        }
    }
    __syncthreads();   // Phi + flags initialized

    const int aoff0 = cq * PKS + 8 * q;          // A-frag rows cq / 16+cq
    const int aoff1 = (16 + cq) * PKS + 8 * q;
    volatile int* vf = flags;

    // acc for chunk 0 = bias of variable w (chunk 0 has no prefix)
    f32x4 acc[2][2];
    {
        const float2 b2 = *(const float2*)(Bt + ((size_t)w * 16 + cq) * 2);
        acc[0][0] = splat4(b2.x); acc[1][0] = splat4(b2.x);
        acc[0][1] = splat4(b2.y); acc[1][1] = splat4(b2.y);
    }

    #pragma unroll 1
    for (int cc = 0; cc < NCH; ++cc) {
        const int v0  = cc * 16;
        const int vme = v0 + w;
        const int nkb = (cc + 1) >> 1;

        // ---- final k-block (cols of chunk cc-1 + zero-padded own cols) ----
        if (cc > 0) {
            while (vf[15] < cc) __builtin_amdgcn_s_sleep(1);
            __threadfence_block();
            const size_t vbase = 16384ull * (size_t)((cc * cc) >> 2)
                               + (size_t)w * 1024ull * nkb + (size_t)lane * 8;
            const int k0 = (nkb - 1) * 32;
            const bf16x8 fa0 = *(const bf16x8*)(Phi + aoff0 + k0);
            const bf16x8 fa1 = *(const bf16x8*)(Phi + aoff1 + k0);
            const bf16x8 fb0 = *(const bf16x8*)(Mb + vbase + (size_t)(nkb - 1) * 512);
            const bf16x8 fb1 = *(const bf16x8*)(Mb + vbase + (size_t)(2 * nkb - 1) * 512);
            acc[0][0] = mfma16(fa0, fb0, acc[0][0]);
            acc[1][0] = mfma16(fa1, fb0, acc[1][0]);
            acc[0][1] = mfma16(fa0, fb1, acc[0][1]);
            acc[1][1] = mfma16(fa1, fb1, acc[1][1]);
        }

        // ---- consume earlier steps' corrections (vl < w) ----
        #pragma unroll 1
        for (int vl = 0; vl < w; ++vl) {
            while (vf[vl] <= cc) __builtin_amdgcn_s_sleep(1);
            __threadfence_block();
            const float2 d2 =
                *(const float2*)(DvT + ((size_t)((v0 + vl) * 16 + w) * 16 + cq) * 2);
            const f32x4 pc0 = *(const f32x4*)(Pc + vl * 32 + 4 * q);
            const f32x4 pc1 = *(const f32x4*)(Pc + vl * 32 + 16 + 4 * q);
            const f32x4 d0s = splat4(d2.x);
            const f32x4 d1s = splat4(d2.y);
            acc[0][0] = __builtin_elementwise_fma(d0s, pc0, acc[0][0]);
            acc[1][0] = __builtin_elementwise_fma(d0s, pc1, acc[1][0]);
            acc[0][1] = __builtin_elementwise_fma(d1s, pc0, acc[0][1]);
            acc[1][1] = __builtin_elementwise_fma(d1s, pc1, acc[1][1]);
        }

        // ---- in-wave reduce over c (16 lanes per q-group); max is exact ----
        f32x4 r00 = acc[0][0], r10 = acc[1][0], r01 = acc[0][1], r11 = acc[1][1];
        #pragma unroll
        for (int m = 1; m < 16; m <<= 1) {
            r00 = __builtin_elementwise_max(r00, shflx4(r00, m));
            r10 = __builtin_elementwise_max(r10, shflx4(r10, m));
            r01 = __builtin_elementwise_max(r01, shflx4(r01, m));
            r11 = __builtin_elementwise_max(r11, shflx4(r11, m));
        }

        // ---- publish: clamp + Pc + Phi column (4 lanes: cq==0, q=0..3) ----
        if (cq == 0) {
            f32x4 po0, po1;
            #pragma unroll
            for (int reg = 0; reg < 4; ++reg) {
                po0[reg] = (float)Phi[(4 * q + reg) * PKS + vme];
                po1[reg] = (float)Phi[(16 + 4 * q + reg) * PKS + vme];
            }
            const f32x4 pc0 = __builtin_elementwise_min(
                                  __builtin_elementwise_max(po0, r00), -r01);
            const f32x4 pc1 = __builtin_elementwise_min(
                                  __builtin_elementwise_max(po1, r10), -r11);
            *(f32x4*)(Pc + w * 32 + 4 * q)      = pc0;
            *(f32x4*)(Pc + w * 32 + 16 + 4 * q) = pc1;
            #pragma unroll
            for (int reg = 0; reg < 4; ++reg) {
                Phi[(4 * q + reg) * PKS + vme]      = (bf16_t)pc0[reg];
                Phi[(16 + 4 * q + reg) * PKS + vme] = (bf16_t)pc1[reg];
            }
        }
        __threadfence_block();
        if (lane == 0) flags[w] = cc + 1;

        // ---- next chunk: bias init + bulk GEMM (cols < 16cc, no wait) ----
        const int ccn = cc + 1;
        if (ccn < NCH) {
            const int nkbN = (ccn + 1) >> 1;
            const size_t vbN = 16384ull * (size_t)((ccn * ccn) >> 2)
                             + (size_t)w * 1024ull * nkbN + (size_t)lane * 8;
            const float2 b2 =
                *(const float2*)(Bt + ((size_t)(ccn * 16 + w) * 16 + cq) * 2);
            acc[0][0] = splat4(b2.x); acc[1][0] = splat4(b2.x);
            acc[0][1] = splat4(b2.y); acc[1][1] = splat4(b2.y);
            #pragma unroll 1
            for (int kb = 0; kb < nkbN - 1; ++kb) {
                const int k0 = kb * 32;
                const bf16x8 fa0 = *(const bf16x8*)(Phi + aoff0 + k0);
                const bf16x8 fa1 = *(const bf16x8*)(Phi + aoff1 + k0);
                const bf16x8 fb0 = *(const bf16x8*)(Mb + vbN + (size_t)kb * 512);
                const bf16x8 fb1 = *(const bf16x8*)(Mb + vbN + (size_t)(nkbN + kb) * 512);
                acc[0][0] = mfma16(fa0, fb0, acc[0][0]);
                acc[1][0] = mfma16(fa1, fb0, acc[1][0]);
                acc[0][1] = mfma16(fa0, fb1, acc[0][1]);
                acc[1][1] = mfma16(fa1, fb1, acc[1][1]);
            }
        }
    }

    __syncthreads();   // all publishes visible

    // ---- epilogue ----
    {
        const int r = tid >> 5, seg = tid & 31;
        float* orow = out + (size_t)(b0 + r) * V + seg * 16;
        #pragma unroll
        for (int k = 0; k < 16; k += 4) {
            const int n = seg * 16 + k;
            float4 o;
            o.x = (float)Phi[r * PKS + n + 0];
            o.y = (float)Phi[r * PKS + n + 1];
            o.z = (float)Phi[r * PKS + n + 2];
            o.w = (float)Phi[r * PKS + n + 3];
            *(float4*)(orow + k) = o;
        }
    }
}

extern "C" void kernel_launch(void* const* d_in, const int* in_sizes, int n_in,
                              void* d_out, int out_size, void* d_ws, size_t ws_size,
                              hipStream_t stream) {
    const float* preds = (const float*)d_in[0];
    const float* pos   = (const float*)d_in[1];
    const float* neg   = (const float*)d_in[2];
    float* o = (float*)d_out;
    char* base = (char*)d_ws;
    bf16_t* Mb  = (bf16_t*)base;
    float*  DvT = (float*)(base + DVT_OFF);
    float*  Bt  = (float*)(base + BT_OFF);
    repack_all<<<dim3(9024), 256, 0, stream>>>(pos, neg, Mb, DvT, Bt);
    shield_async<<<dim3(BATCH / RB), NT, 0, stream>>>(preds, Mb, DvT, Bt, o);
}